// Round 9
// baseline (304.395 us; speedup 1.0000x reference)
//
#include <hip/hip_runtime.h>
#include <stdint.h>

#define VOCAB  32000
#define NSTATE 64
#define NLABEL 16
#define BATCH  512
#define MAXLEN 512
#define CHUNK  64
#define NC     (MAXLEN / CHUNK)   // 8 chunks of 64 steps

#define LOG2E 1.44269504088896340736f
#define LN2_D 0.69314718055994530942

typedef float  f32x4  __attribute__((ext_vector_type(4)));
typedef short  bf16x8 __attribute__((ext_vector_type(8)));
typedef float  v2f    __attribute__((ext_vector_type(2)));

#if defined(__has_builtin) && __has_builtin(__builtin_amdgcn_exp2f)
#define EXP2(x) __builtin_amdgcn_exp2f(x)
#else
#define EXP2(x) exp2f(x)
#endif
#if defined(__has_builtin) && __has_builtin(__builtin_amdgcn_logf)
#define LOG2(x) __builtin_amdgcn_logf(x)
#else
#define LOG2(x) log2f(x)
#endif

__device__ __forceinline__ float wave_max64(float x) {
#pragma unroll
  for (int off = 32; off > 0; off >>= 1) x = fmaxf(x, __shfl_xor(x, off, 64));
  return x;
}
__device__ __forceinline__ float wave_sum64(float x) {
#pragma unroll
  for (int off = 32; off > 0; off >>= 1) x += __shfl_xor(x, off, 64);
  return x;
}
__device__ __forceinline__ float bcast0(float x) {
  return __uint_as_float(__builtin_amdgcn_readfirstlane(__float_as_uint(x)));
}
__device__ __forceinline__ double shfl_xor_d(double x, int off) {
  union { double d; int i[2]; } u;
  u.d = x;
  u.i[0] = __shfl_xor(u.i[0], off, 64);
  u.i[1] = __shfl_xor(u.i[1], off, 64);
  return u.d;
}
// f32 -> bf16 (RNE)
__device__ __forceinline__ unsigned short f2bf(float x) {
  uint32_t u = __float_as_uint(x);
  return (unsigned short)((u + 0x7FFFu + ((u >> 16) & 1u)) >> 16);
}
__device__ __forceinline__ float bf2f(unsigned short h) {
  return __uint_as_float(((uint32_t)h) << 16);
}
// LDS bank swizzle for the MT tile: XOR row-bits into the 16B-slot bits.
__device__ __forceinline__ int swz(int a) { return a ^ (((a >> 7) & 7) << 4); }

// --- prep 1: emb2[w][s] = log2_softmax(emb[w]*log2e) ---
__global__ void prep_emb_k(const float* __restrict__ emb, float* __restrict__ emb2) {
  const int w = blockIdx.x * 4 + (threadIdx.x >> 6);
  const int s = threadIdx.x & 63;
  const float v = emb[w * NSTATE + s] * LOG2E;
  const float m = wave_max64(v);
  const float ss = wave_sum64(EXP2(v - m));
  emb2[w * NSTATE + s] = v - m - LOG2(ss);
}

// --- prep 2: W = softmax(transition) rows (f32); out2 = log2_softmax(output) ---
__global__ void prep_mats_k(const float* __restrict__ trans, const float* __restrict__ outp,
                            float* __restrict__ W, float* __restrict__ out2) {
  const int r = blockIdx.x, s = threadIdx.x;
  if (r < NSTATE) {
    const float v = trans[r * NSTATE + s] * LOG2E;
    const float m = wave_max64(v);
    const float ss = wave_sum64(EXP2(v - m));
    W[r * NSTATE + s] = EXP2(v - m - LOG2(ss));
  } else {
    const int l = r - NSTATE;
    const float v = outp[l * NSTATE + s] * LOG2E;
    const float m = wave_max64(v);
    const float ss = wave_sum64(EXP2(v - m));
    out2[l * NSTATE + s] = v - m - LOG2(ss);
  }
}

// --- prep 3: W f32 -> bf16 MFMA A-fragments.
// A-frag for mfma_f32_16x16x32_bf16: lane l holds A[row][k], row = mi*16+(l&15),
// k = ks*32 + 8*(l>>4) + i (i=0..7). Wb[((mi*2+ks)*64 + l)] = that bf16x8.
__global__ void prep_wfrag_k(const float* __restrict__ W, bf16x8* __restrict__ Wb) {
  const int l = threadIdx.x;
  const int l15 = l & 15, lh = l >> 4;
#pragma unroll
  for (int mi = 0; mi < 4; ++mi)
#pragma unroll
    for (int ks = 0; ks < 2; ++ks) {
      bf16x8 v;
#pragma unroll
      for (int i = 0; i < 8; ++i)
        v[i] = (short)f2bf(W[(mi * 16 + l15) * 64 + ks * 32 + 8 * lh + i]);
      Wb[(mi * 2 + ks) * 64 + l] = v;
    }
}

// --- prep 4: musum[b] = sum_{t<len} emb2[id_t][0]  (f64) ---
__global__ void prep_musum2_k(const int* __restrict__ sents, const float* __restrict__ emb2,
                              const int* __restrict__ length, double* __restrict__ musum) {
  const int b = blockIdx.x;
  const int l = threadIdx.x;
  const int len = length[b];
  double acc = 0.0;
#pragma unroll
  for (int k = 0; k < 8; ++k) {
    const int t = k * 64 + l;
    const int id = sents[b * MAXLEN + t];
    const float e0 = emb2[id * NSTATE];
    if (t < len) acc += (double)e0;
  }
#pragma unroll
  for (int off = 32; off > 0; off >>= 1) acc += shfl_xor_d(acc, off);
  if (l == 0) musum[b] = acc;
}

// --- phase A: per (b, chunk) compute M = Prod_{t desc} D(q_t) W  (64x64, bf16) ---
// One wave per task. M lives in LDS as MT[n][k] (n = output column, k = row index
// of the product = next contraction index), byte (n*64+k)*2, XOR-swizzled.
// W (A-operand) is static in registers. q gathered inline from emb2.
__global__ __launch_bounds__(64, 2) void phaseA_k(
    const int* __restrict__ sents, const int* __restrict__ length,
    const float* __restrict__ emb2, const bf16x8* __restrict__ Wb,
    unsigned short* __restrict__ Mout, int* __restrict__ Mexp) {
  const int tid = blockIdx.x;
  const int b = tid >> 3;     // NC = 8
  const int c = tid & 7;
  const int l = threadIdx.x;
  const int l15 = l & 15, lh = l >> 4;

  __shared__ __align__(16) unsigned short MT[4096];   // 8 KB
  __shared__ __align__(16) float q_lds[NSTATE];
  __shared__ __align__(16) int ids[CHUNK];

  ids[l] = sents[b * MAXLEN + c * CHUNK + l];

  bf16x8 wf[4][2];
#pragma unroll
  for (int mi = 0; mi < 4; ++mi)
#pragma unroll
    for (int ks = 0; ks < 2; ++ks)
      wf[mi][ks] = Wb[(mi * 2 + ks) * 64 + l];

  // MT = Identity (zero fill, then diagonal). Single-wave: LDS ops in order.
  {
    const int4 z{0, 0, 0, 0};
#pragma unroll
    for (int k = 0; k < 8; ++k)
      *reinterpret_cast<int4*>(reinterpret_cast<char*>(MT) + k * 1024 + l * 16) = z;
    const int dbyte = swz(128 * l + 2 * l);
    *reinterpret_cast<unsigned short*>(reinterpret_cast<char*>(MT) + dbyte) = 0x3F80u;  // bf16 1.0
  }

  const int len = length[b];
  const int t0 = c * CHUNK;
  const int start = (c == 0) ? 1 : t0;
  const int end_ = ((len - 1) < (t0 + CHUNK - 1)) ? (len - 1) : (t0 + CHUNK - 1);
  const int K = end_ - start + 1;
  int MUc = 0;

  if (K > 0) {
    int idx = start - t0;
    int idc = ids[idx];                       // uniform -> broadcast read
    float e_cur = emb2[idc * NSTATE + l];
    float rnorm = 1.0f;
    bool rn_pending = false;

    for (int j = 0; j < K; ++j) {
      // prefetch next emission row (independent of this step's compute)
      const int idxn = (j + 1 < K) ? (idx + 1) : idx;
      const int idn = ids[idxn];
      const float e_nxt = emb2[idn * NSTATE + l];

      const float se = bcast0(e_cur);         // e_t[0]; lane 0 holds state 0
      q_lds[l] = EXP2(e_cur - se);

      float samp = 0.f;
#pragma unroll
      for (int pass = 0; pass < 2; ++pass) {  // ni pairs {0,1} then {2,3}
        // B-frags: lane holds M[k][n], n = ni*16+(l&15), k = ks*32+8*(l>>4)+i
        bf16x8 mf[2][2];
#pragma unroll
        for (int ks = 0; ks < 2; ++ks)
#pragma unroll
          for (int nn = 0; nn < 2; ++nn) {
            const int n = (pass * 2 + nn) * 16 + l15;
            const int byte = swz(128 * n + 64 * ks + 16 * lh);
            mf[ks][nn] = *reinterpret_cast<const bf16x8*>(
                reinterpret_cast<const char*>(MT) + byte);
          }
#pragma unroll
        for (int mi = 0; mi < 4; ++mi) {
          f32x4 qf = *reinterpret_cast<const f32x4*>(q_lds + mi * 16 + 4 * lh);
          if (rn_pending) qf *= rnorm;
#pragma unroll
          for (int nn = 0; nn < 2; ++nn) {
            f32x4 acc{0.f, 0.f, 0.f, 0.f};
            acc = __builtin_amdgcn_mfma_f32_16x16x32_bf16(wf[mi][0], mf[0][nn], acc, 0, 0, 0);
            acc = __builtin_amdgcn_mfma_f32_16x16x32_bf16(wf[mi][1], mf[1][nn], acc, 0, 0, 0);
            // C layout (verified): col n = l&15 (+tile), row = mi*16 + 4*(l>>4) + r
            acc *= qf;                         // row scale by q
            if (pass == 0 && nn == 0 && mi == 0) samp = acc.x;  // lane0 -> N[0][0]q[0]
            const uint32_t lo = (uint32_t)f2bf(acc.x) | ((uint32_t)f2bf(acc.y) << 16);
            const uint32_t hi = (uint32_t)f2bf(acc.z) | ((uint32_t)f2bf(acc.w) << 16);
            const int n = (pass * 2 + nn) * 16 + l15;
            const int wbyte = swz(128 * n + 2 * (mi * 16 + 4 * lh));
            *reinterpret_cast<uint2*>(reinterpret_cast<char*>(MT) + wbyte) = uint2{lo, hi};
          }
        }
      }
      // exact power-of-two renorm (correction applied next step; exponent tracked)
      rn_pending = false;
      if (((j & 7) == 7) && (j + 1 < K)) {
        const uint32_t u = __builtin_amdgcn_readfirstlane(__float_as_uint(samp));
        const int ex = (int)((u >> 23) & 255u) - 127;
        rnorm = __uint_as_float((uint32_t)(127 - ex) << 23);
        rn_pending = true;
        MUc += ex;
      }
      e_cur = e_nxt;
      idx = idxn;
    }
  }

  // writeout: raw (still-swizzled) 8KB image + exponent
  unsigned short* dst = Mout + (size_t)tid * 4096;
#pragma unroll
  for (int k = 0; k < 8; ++k) {
    const int4 v = *reinterpret_cast<const int4*>(
        reinterpret_cast<const char*>(MT) + k * 1024 + l * 16);
    *reinterpret_cast<int4*>(reinterpret_cast<char*>(dst) + k * 1024 + l * 16) = v;
  }
  if (l == 0) Mexp[tid] = MUc;
}

// --- phase B: per row, p0 -> 8 sequential matvecs -> epilogue ---
__global__ __launch_bounds__(64) void phaseB_k(
    const int* __restrict__ sents, const int* __restrict__ length,
    const float* __restrict__ emb2, const float* __restrict__ out2,
    const unsigned short* __restrict__ Mout, const int* __restrict__ Mexp,
    const double* __restrict__ musum, float* __restrict__ score) {
  const int b = blockIdx.x;
  const int l = threadIdx.x;
  const int len = length[b];

  const int id0 = sents[b * MAXLEN];
  const float e0 = emb2[id0 * NSTATE + l];
  const float se0 = bcast0(e0);
  float p = EXP2(e0 - se0);
  int MUi = 0;

  for (int c = 0; c < NC && c * CHUNK < len; ++c) {
    const unsigned short* M = Mout + ((size_t)(b * NC + c)) * 4096;
    float acc = 0.f;
    // p_new[m] = sum_n MT[n][m] * p[n]; lane = m
#pragma unroll 8
    for (int n = 0; n < 64; ++n) {
      const float pn = __shfl(p, n, 64);
      const int byte = swz(128 * n + 2 * l);
      const unsigned short h = *reinterpret_cast<const unsigned short*>(
          reinterpret_cast<const char*>(M) + byte);
      acc = fmaf(bf2f(h), pn, acc);
    }
    p = acc;
    MUi += Mexp[b * NC + c];
    const uint32_t u = __builtin_amdgcn_readfirstlane(__float_as_uint(p));
    const int ex = (int)((u >> 23) & 255u) - 127;
    p *= __uint_as_float((uint32_t)(127 - ex) << 23);
    MUi += ex;
  }

  const float f = LOG2(p);
  const double base = musum[b] + (double)MUi;
  for (int ll = 0; ll < NLABEL; ++ll) {
    const float y = out2[ll * NSTATE + l] + f;
    const float m = wave_max64(y);
    const float ssum = wave_sum64(EXP2(y - m));
    if (l == 0)
      score[b * NLABEL + ll] = (float)((base + (double)m + (double)LOG2(ssum)) * LN2_D);
  }
}

// ================= fallback (only if ws is too small; self-contained) =================
__global__ __launch_bounds__(64, 1) void iohmm_fwd_fb(
    const int* __restrict__ sents, const int* __restrict__ length,
    const float* __restrict__ emb, const float* __restrict__ trans,
    const float* __restrict__ outp, float* __restrict__ score) {
  const int b = blockIdx.x;
  const int s = threadIdx.x;
  __shared__ __align__(16) float p_lds[2][NSTATE];
  v2f w2[NSTATE / 2];
  {
    float wr[NSTATE];
#pragma unroll
    for (int j = 0; j < 16; ++j) {
      const float4 q = *reinterpret_cast<const float4*>(trans + s * NSTATE + 4 * j);
      wr[4 * j + 0] = q.x * LOG2E; wr[4 * j + 1] = q.y * LOG2E;
      wr[4 * j + 2] = q.z * LOG2E; wr[4 * j + 3] = q.w * LOG2E;
    }
    float m = -1e30f;
#pragma unroll
    for (int j = 0; j < NSTATE; ++j) m = fmaxf(m, wr[j]);
    float ss = 0.f;
#pragma unroll
    for (int j = 0; j < NSTATE; ++j) ss += EXP2(wr[j] - m);
    const float d = m + LOG2(ss);
#pragma unroll
    for (int j = 0; j < NSTATE / 2; ++j)
      w2[j] = v2f{EXP2(wr[2 * j] - d), EXP2(wr[2 * j + 1] - d)};
  }
  const int len = length[b];
  auto EMIT = [&](int t) -> float {
    const int tc = t < MAXLEN ? t : MAXLEN - 1;
    return emb[sents[b * MAXLEN + tc] * NSTATE + s] * LOG2E;
  };
  float e0 = EMIT(0);
  {
    const float dm = wave_max64(e0);
    const float dsum = wave_sum64(EXP2(e0 - dm));
    e0 = e0 - dm - LOG2(dsum);
  }
  const float se0 = bcast0(e0);
  float p = EXP2(e0 - se0);
  double MU = (double)se0;
  int MUi = 0;
  for (int t = 1; t < len; ++t) {
    float* pb = p_lds[t & 1];
    pb[s] = p;
    __builtin_amdgcn_sched_barrier(0);
    const float eR = EMIT(t);
    const float4* pb4 = reinterpret_cast<const float4*>(pb);
    v2f A0{0.f, 0.f}, A1 = A0, A2 = A0, A3 = A0;
#pragma unroll
    for (int j = 0; j < 8; ++j) {
      const float4 qa = pb4[2 * j + 0];
      const float4 qb = pb4[2 * j + 1];
      A0 = __builtin_elementwise_fma(w2[4 * j + 0], v2f{qa.x, qa.y}, A0);
      A1 = __builtin_elementwise_fma(w2[4 * j + 1], v2f{qa.z, qa.w}, A1);
      A2 = __builtin_elementwise_fma(w2[4 * j + 2], v2f{qb.x, qb.y}, A2);
      A3 = __builtin_elementwise_fma(w2[4 * j + 3], v2f{qb.z, qb.w}, A3);
    }
    const v2f S0 = A0 + A2, S1 = A1 + A3;
    const v2f U = S0 + S1;
    const float sum = U.x + U.y;
    const float dm = wave_max64(eR);
    const float dsum = wave_sum64(EXP2(eR - dm));
    const float e = eR - dm - LOG2(dsum);
    const float se = bcast0(e);
    p = sum * EXP2(e - se);
    if ((t & 15) == 0) {
      const uint32_t u = __builtin_amdgcn_readfirstlane(__float_as_uint(p));
      const int ex = (int)((u >> 23) & 255u) - 127;
      p *= __uint_as_float((uint32_t)(127 - ex) << 23);
      MUi += ex;
    }
    MU += (double)se;
  }
  const float f = LOG2(p);
  const double MUt = MU + (double)MUi;
  for (int ll = 0; ll < NLABEL; ++ll) {
    const float v = outp[ll * NSTATE + s] * LOG2E;
    const float lm = wave_max64(v);
    const float lsum = wave_sum64(EXP2(v - lm));
    const float y = v - lm - LOG2(lsum) + f;
    const float m = wave_max64(y);
    const float ssum = wave_sum64(EXP2(y - m));
    if (s == 0)
      score[b * NLABEL + ll] = (float)((MUt + (double)m + (double)LOG2(ssum)) * LN2_D);
  }
}

extern "C" void kernel_launch(void* const* d_in, const int* in_sizes, int n_in,
                              void* d_out, int out_size, void* d_ws, size_t ws_size,
                              hipStream_t stream) {
  const int* sents = (const int*)d_in[0];
  const int* length = (const int*)d_in[1];
  const float* emb = (const float*)d_in[2];
  const float* trans = (const float*)d_in[3];
  const float* outp = (const float*)d_in[4];
  float* score = (float*)d_out;

  // ws layout
  const size_t emb2_off = 0;
  const size_t emb2_sz = (size_t)VOCAB * NSTATE * sizeof(float);            // 8,192,000
  const size_t W_off = emb2_off + emb2_sz;
  const size_t W_sz = NSTATE * NSTATE * sizeof(float);                      // 16,384
  const size_t out2_off = W_off + W_sz;
  const size_t out2_sz = NLABEL * NSTATE * sizeof(float);                   // 4,096
  const size_t Wb_off = out2_off + out2_sz;
  const size_t Wb_sz = 8 * 64 * 16;                                         // 8,192
  const size_t musum_off = Wb_off + Wb_sz;
  const size_t musum_sz = BATCH * sizeof(double);                           // 4,096
  const size_t Mexp_off = musum_off + musum_sz;
  const size_t Mexp_sz = (size_t)BATCH * NC * sizeof(int);                  // 16,384
  const size_t Mout_off = Mexp_off + Mexp_sz;
  const size_t Mout_sz = (size_t)BATCH * NC * 4096 * sizeof(unsigned short);// 33,554,432
  const size_t need = Mout_off + Mout_sz;                                   // ~41.8 MB

  if (ws_size >= need) {
    float* emb2 = (float*)((char*)d_ws + emb2_off);
    float* W = (float*)((char*)d_ws + W_off);
    float* out2 = (float*)((char*)d_ws + out2_off);
    bf16x8* Wb = (bf16x8*)((char*)d_ws + Wb_off);
    double* musum = (double*)((char*)d_ws + musum_off);
    int* Mexp = (int*)((char*)d_ws + Mexp_off);
    unsigned short* Mout = (unsigned short*)((char*)d_ws + Mout_off);

    prep_emb_k<<<VOCAB / 4, 256, 0, stream>>>(emb, emb2);
    prep_mats_k<<<NSTATE + NLABEL, 64, 0, stream>>>(trans, outp, W, out2);
    prep_wfrag_k<<<1, 64, 0, stream>>>(W, Wb);
    prep_musum2_k<<<BATCH, 64, 0, stream>>>(sents, emb2, length, musum);
    phaseA_k<<<BATCH * NC, 64, 0, stream>>>(sents, length, emb2, Wb, Mout, Mexp);
    phaseB_k<<<BATCH, 64, 0, stream>>>(sents, length, emb2, out2, Mout, Mexp, musum, score);
  } else {
    iohmm_fwd_fb<<<BATCH, 64, 0, stream>>>(sents, length, emb, trans, outp, score);
  }
}

// Round 12
// 283.012 us; speedup vs baseline: 1.0756x; 1.0756x over previous
//
#include <hip/hip_runtime.h>
#include <hip/hip_bf16.h>
#include <stdint.h>

#define VOCAB  32000
#define NSTATE 64
#define NLABEL 16
#define BATCH  512
#define MAXLEN 512
#define CHUNK  64
#define NC     (MAXLEN / CHUNK)   // 8 chunks of 64 steps

#define LOG2E 1.44269504088896340736f
#define LN2_D 0.69314718055994530942

typedef float  f32x4  __attribute__((ext_vector_type(4)));
typedef short  bf16x8 __attribute__((ext_vector_type(8)));
typedef float  v2f    __attribute__((ext_vector_type(2)));

#if defined(__has_builtin) && __has_builtin(__builtin_amdgcn_exp2f)
#define EXP2(x) __builtin_amdgcn_exp2f(x)
#else
#define EXP2(x) exp2f(x)
#endif
#if defined(__has_builtin) && __has_builtin(__builtin_amdgcn_logf)
#define LOG2(x) __builtin_amdgcn_logf(x)
#else
#define LOG2(x) log2f(x)
#endif

__device__ __forceinline__ float wave_max64(float x) {
#pragma unroll
  for (int off = 32; off > 0; off >>= 1) x = fmaxf(x, __shfl_xor(x, off, 64));
  return x;
}
__device__ __forceinline__ float wave_sum64(float x) {
#pragma unroll
  for (int off = 32; off > 0; off >>= 1) x += __shfl_xor(x, off, 64);
  return x;
}
__device__ __forceinline__ float bcast0(float x) {
  return __uint_as_float(__builtin_amdgcn_readfirstlane(__float_as_uint(x)));
}
__device__ __forceinline__ double shfl_xor_d(double x, int off) {
  union { double d; int i[2]; } u;
  u.d = x;
  u.i[0] = __shfl_xor(u.i[0], off, 64);
  u.i[1] = __shfl_xor(u.i[1], off, 64);
  return u.d;
}
// f32 -> bf16 via HIP cast (compiler emits v_cvt / pairs to v_cvt_pk_bf16_f32)
__device__ __forceinline__ short bfs(float x) {
  __hip_bfloat16 h = __float2bfloat16(x);
  return *reinterpret_cast<short*>(&h);
}
__device__ __forceinline__ uint32_t pkbf(float lo, float hi) {
  return (uint32_t)(unsigned short)bfs(lo) | ((uint32_t)(unsigned short)bfs(hi) << 16);
}
__device__ __forceinline__ float bf2f(unsigned short h) {
  return __uint_as_float(((uint32_t)h) << 16);
}
// LDS bank swizzle for the 8KB MT tile: XOR row bits into the 16B-slot bits.
__device__ __forceinline__ int swz(int a) { return a ^ (((a >> 7) & 7) << 4); }

// --- prep 1: emb2[w][s] = log2_softmax(emb[w]*log2e) ---
__global__ void prep_emb_k(const float* __restrict__ emb, float* __restrict__ emb2) {
  const int w = blockIdx.x * 4 + (threadIdx.x >> 6);
  const int s = threadIdx.x & 63;
  const float v = emb[w * NSTATE + s] * LOG2E;
  const float m = wave_max64(v);
  const float ss = wave_sum64(EXP2(v - m));
  emb2[w * NSTATE + s] = v - m - LOG2(ss);
}

// --- prep 2: W = softmax(transition) rows (f32); out2 = log2_softmax(output) ---
__global__ void prep_mats_k(const float* __restrict__ trans, const float* __restrict__ outp,
                            float* __restrict__ W, float* __restrict__ out2) {
  const int r = blockIdx.x, s = threadIdx.x;
  if (r < NSTATE) {
    const float v = trans[r * NSTATE + s] * LOG2E;
    const float m = wave_max64(v);
    const float ss = wave_sum64(EXP2(v - m));
    W[r * NSTATE + s] = EXP2(v - m - LOG2(ss));
  } else {
    const int l = r - NSTATE;
    const float v = outp[l * NSTATE + s] * LOG2E;
    const float m = wave_max64(v);
    const float ss = wave_sum64(EXP2(v - m));
    out2[l * NSTATE + s] = v - m - LOG2(ss);
  }
}

// --- phase A: per (b, chunk) compute M = Prod_{t desc} D(q_t) W  (64x64, bf16) ---
// 4 independent waves per 256-thr block (forces 16 waves/CU residency at 32KB LDS).
// M lives in per-wave LDS as MT[n][row], XOR-swizzled; W A-frags built in prologue.
__global__ __launch_bounds__(256, 4) void phaseA_k(
    const int* __restrict__ sents, const int* __restrict__ length,
    const float* __restrict__ emb2, const float* __restrict__ W,
    unsigned short* __restrict__ Mout, int* __restrict__ Mexp) {
  const int wid = threadIdx.x >> 6;
  const int l = threadIdx.x & 63;
  const int tid = blockIdx.x * 4 + wid;
  const int b = tid >> 3;     // NC = 8
  const int c = tid & 7;
  const int l15 = l & 15, lh = l >> 4;

  __shared__ __align__(16) unsigned short MTall[4][4096];   // 8 KB per wave
  char* MTc = reinterpret_cast<char*>(MTall[wid]);

  // word ids for this chunk live in a register; step t's id = __shfl(myid, t)
  const int myid = sents[b * MAXLEN + c * CHUNK + l];

  // build W bf16 A-frags from f32 W: lane holds A[row=mi*16+l15][k=ks*32+8*lh+i]
  bf16x8 wf[4][2];
#pragma unroll
  for (int mi = 0; mi < 4; ++mi)
#pragma unroll
    for (int ks = 0; ks < 2; ++ks) {
      const float* wp = W + (mi * 16 + l15) * 64 + ks * 32 + 8 * lh;
      const float4 a = *reinterpret_cast<const float4*>(wp);
      const float4 d = *reinterpret_cast<const float4*>(wp + 4);
      bf16x8 v;
      v[0] = bfs(a.x); v[1] = bfs(a.y); v[2] = bfs(a.z); v[3] = bfs(a.w);
      v[4] = bfs(d.x); v[5] = bfs(d.y); v[6] = bfs(d.z); v[7] = bfs(d.w);
      wf[mi][ks] = v;
    }

  // MT = Identity (zero fill, then diagonal). Single-wave region: in-order LDS.
  {
    const int4 z{0, 0, 0, 0};
#pragma unroll
    for (int k = 0; k < 8; ++k)
      *reinterpret_cast<int4*>(MTc + k * 1024 + l * 16) = z;
    *reinterpret_cast<unsigned short*>(MTc + swz(130 * l)) = 0x3F80u;  // bf16 1.0
  }

  const int len = length[b];
  const int t0 = c * CHUNK;
  const int start = (c == 0) ? 1 : t0;
  const int end_ = ((len - 1) < (t0 + CHUNK - 1)) ? (len - 1) : (t0 + CHUNK - 1);
  const int K = end_ - start + 1;
  int MUc = 0;

  if (K > 0) {
    const int lastj = end_ - t0;
    const int j0 = start - t0;
    // emission prefetch pipeline, distance 2 (covers ~500-700cyc L3 latency)
    float eA = emb2[(size_t)__shfl(myid, j0, 64) * 64 + l];
    const int j1 = (j0 + 1 <= lastj) ? j0 + 1 : lastj;
    float eB = emb2[(size_t)__shfl(myid, j1, 64) * 64 + l];
    float rnorm = 1.0f;
    bool rnp = false;

    for (int j = 0; j < K; ++j) {
      int jn = j0 + j + 2; jn = (jn <= lastj) ? jn : lastj;
      const float eC = emb2[(size_t)__shfl(myid, jn, 64) * 64 + l];

      const float se = bcast0(eA);            // e_t[0]; lane 0 holds state 0
      float qv = EXP2(eA - se);
      if (rnp) qv *= rnorm;                   // uniform pow2 renorm correction

      // q-scale factors for this lane's acc rows (16*mi + 4*lh + r), via shuffles
      float qsc[4][4];
#pragma unroll
      for (int mi = 0; mi < 4; ++mi)
#pragma unroll
        for (int r = 0; r < 4; ++r)
          qsc[mi][r] = __shfl(qv, mi * 16 + 4 * lh + r, 64);

      float samp = 0.f;
#pragma unroll
      for (int pass = 0; pass < 2; ++pass) {  // n-halves {0,1} then {2,3}
        // B-frags: lane holds M[k][n], n = (pass*2+nn)*16+l15, k = ks*32+8*lh+i
        bf16x8 mf[2][2];
#pragma unroll
        for (int ks = 0; ks < 2; ++ks)
#pragma unroll
          for (int nn = 0; nn < 2; ++nn) {
            const int n = (pass * 2 + nn) * 16 + l15;
            mf[ks][nn] = *reinterpret_cast<const bf16x8*>(
                MTc + swz(128 * n + 64 * ks + 16 * lh));
          }
#pragma unroll
        for (int mi = 0; mi < 4; ++mi) {
#pragma unroll
          for (int nn = 0; nn < 2; ++nn) {
            f32x4 acc{0.f, 0.f, 0.f, 0.f};
            acc = __builtin_amdgcn_mfma_f32_16x16x32_bf16(wf[mi][0], mf[0][nn], acc, 0, 0, 0);
            acc = __builtin_amdgcn_mfma_f32_16x16x32_bf16(wf[mi][1], mf[1][nn], acc, 0, 0, 0);
            // C layout: col n = l15 (+tile), row = mi*16 + 4*lh + r
            acc.x *= qsc[mi][0]; acc.y *= qsc[mi][1];
            acc.z *= qsc[mi][2]; acc.w *= qsc[mi][3];
            if (pass == 0 && nn == 0 && mi == 0) samp = acc.x;  // lane0: N[0][0]q[0]
            const uint32_t lo = pkbf(acc.x, acc.y);
            const uint32_t hi = pkbf(acc.z, acc.w);
            const int n = (pass * 2 + nn) * 16 + l15;
            *reinterpret_cast<uint2*>(MTc + swz(128 * n + 32 * mi + 8 * lh)) =
                uint2{lo, hi};
          }
        }
      }
      rnp = false;
      if (((j & 7) == 7) && (j + 1 < K)) {   // exact pow2 renorm every 8 steps
        const uint32_t u = __builtin_amdgcn_readfirstlane(__float_as_uint(samp));
        const int ex = (int)((u >> 23) & 255u) - 127;
        rnorm = __uint_as_float((uint32_t)(127 - ex) << 23);
        rnp = true;
        MUc += ex;
      }
      eA = eB; eB = eC;
    }
  }

  // writeout: raw (still-swizzled) 8KB image + exponent
  unsigned short* dst = Mout + (size_t)tid * 4096;
#pragma unroll
  for (int k = 0; k < 8; ++k) {
    const int4 v = *reinterpret_cast<const int4*>(MTc + k * 1024 + l * 16);
    *reinterpret_cast<int4*>(reinterpret_cast<char*>(dst) + k * 1024 + l * 16) = v;
  }
  if (l == 0) Mexp[tid] = MUc;
}

// --- phase B: per row, p0 -> 8 sequential matvecs -> epilogue (musum folded in) ---
__global__ __launch_bounds__(64) void phaseB_k(
    const int* __restrict__ sents, const int* __restrict__ length,
    const float* __restrict__ emb2, const float* __restrict__ out2,
    const unsigned short* __restrict__ Mout, const int* __restrict__ Mexp,
    float* __restrict__ score) {
  const int b = blockIdx.x;
  const int l = threadIdx.x;
  const int len = length[b];

  // musum[b] = sum_{t<len} emb2[id_t][0]  (f64, wave-reduced; loads overlap below)
  double ms = 0.0;
#pragma unroll
  for (int k = 0; k < 8; ++k) {
    const int t = k * 64 + l;
    const int id = sents[b * MAXLEN + t];
    const float e0 = emb2[(size_t)id * NSTATE];
    if (t < len) ms += (double)e0;
  }

  const int id0 = sents[b * MAXLEN];
  const float e0 = emb2[(size_t)id0 * NSTATE + l];
  const float se0 = bcast0(e0);
  float p = EXP2(e0 - se0);
  int MUi = 0;

  for (int c = 0; c < NC && c * CHUNK < len; ++c) {
    const unsigned short* M = Mout + ((size_t)(b * NC + c)) * 4096;
    float acc = 0.f;
    // p_new[m] = sum_n MT[n][m] * p[n]; lane = m
#pragma unroll 8
    for (int n = 0; n < 64; ++n) {
      const float pn = __shfl(p, n, 64);
      const unsigned short h = *reinterpret_cast<const unsigned short*>(
          reinterpret_cast<const char*>(M) + swz(128 * n + 2 * l));
      acc = fmaf(bf2f(h), pn, acc);
    }
    p = acc;
    MUi += Mexp[b * NC + c];
    const uint32_t u = __builtin_amdgcn_readfirstlane(__float_as_uint(p));
    const int ex = (int)((u >> 23) & 255u) - 127;
    p *= __uint_as_float((uint32_t)(127 - ex) << 23);
    MUi += ex;
  }

#pragma unroll
  for (int off = 32; off > 0; off >>= 1) ms += shfl_xor_d(ms, off);

  const float f = LOG2(p);
  const double base = ms + (double)MUi;
  for (int ll = 0; ll < NLABEL; ++ll) {
    const float y = out2[ll * NSTATE + l] + f;
    const float m = wave_max64(y);
    const float ssum = wave_sum64(EXP2(y - m));
    if (l == 0)
      score[b * NLABEL + ll] = (float)((base + (double)m + (double)LOG2(ssum)) * LN2_D);
  }
}

// ================= fallback (only if ws is too small; self-contained) =================
__global__ __launch_bounds__(64, 1) void iohmm_fwd_fb(
    const int* __restrict__ sents, const int* __restrict__ length,
    const float* __restrict__ emb, const float* __restrict__ trans,
    const float* __restrict__ outp, float* __restrict__ score) {
  const int b = blockIdx.x;
  const int s = threadIdx.x;
  __shared__ __align__(16) float p_lds[2][NSTATE];
  v2f w2[NSTATE / 2];
  {
    float wr[NSTATE];
#pragma unroll
    for (int j = 0; j < 16; ++j) {
      const float4 q = *reinterpret_cast<const float4*>(trans + s * NSTATE + 4 * j);
      wr[4 * j + 0] = q.x * LOG2E; wr[4 * j + 1] = q.y * LOG2E;
      wr[4 * j + 2] = q.z * LOG2E; wr[4 * j + 3] = q.w * LOG2E;
    }
    float m = -1e30f;
#pragma unroll
    for (int j = 0; j < NSTATE; ++j) m = fmaxf(m, wr[j]);
    float ss = 0.f;
#pragma unroll
    for (int j = 0; j < NSTATE; ++j) ss += EXP2(wr[j] - m);
    const float d = m + LOG2(ss);
#pragma unroll
    for (int j = 0; j < NSTATE / 2; ++j)
      w2[j] = v2f{EXP2(wr[2 * j] - d), EXP2(wr[2 * j + 1] - d)};
  }
  const int len = length[b];
  auto EMIT = [&](int t) -> float {
    const int tc = t < MAXLEN ? t : MAXLEN - 1;
    return emb[sents[b * MAXLEN + tc] * NSTATE + s] * LOG2E;
  };
  float e0 = EMIT(0);
  {
    const float dm = wave_max64(e0);
    const float dsum = wave_sum64(EXP2(e0 - dm));
    e0 = e0 - dm - LOG2(dsum);
  }
  const float se0 = bcast0(e0);
  float p = EXP2(e0 - se0);
  double MU = (double)se0;
  int MUi = 0;
  for (int t = 1; t < len; ++t) {
    float* pb = p_lds[t & 1];
    pb[s] = p;
    __builtin_amdgcn_sched_barrier(0);
    const float eR = EMIT(t);
    const float4* pb4 = reinterpret_cast<const float4*>(pb);
    v2f A0{0.f, 0.f}, A1 = A0, A2 = A0, A3 = A0;
#pragma unroll
    for (int j = 0; j < 8; ++j) {
      const float4 qa = pb4[2 * j + 0];
      const float4 qb = pb4[2 * j + 1];
      A0 = __builtin_elementwise_fma(w2[4 * j + 0], v2f{qa.x, qa.y}, A0);
      A1 = __builtin_elementwise_fma(w2[4 * j + 1], v2f{qa.z, qa.w}, A1);
      A2 = __builtin_elementwise_fma(w2[4 * j + 2], v2f{qb.x, qb.y}, A2);
      A3 = __builtin_elementwise_fma(w2[4 * j + 3], v2f{qb.z, qb.w}, A3);
    }
    const v2f S0 = A0 + A2, S1 = A1 + A3;
    const v2f U = S0 + S1;
    const float sum = U.x + U.y;
    const float dm = wave_max64(eR);
    const float dsum = wave_sum64(EXP2(eR - dm));
    const float e = eR - dm - LOG2(dsum);
    const float se = bcast0(e);
    p = sum * EXP2(e - se);
    if ((t & 15) == 0) {
      const uint32_t u = __builtin_amdgcn_readfirstlane(__float_as_uint(p));
      const int ex = (int)((u >> 23) & 255u) - 127;
      p *= __uint_as_float((uint32_t)(127 - ex) << 23);
      MUi += ex;
    }
    MU += (double)se;
  }
  const float f = LOG2(p);
  const double MUt = MU + (double)MUi;
  for (int ll = 0; ll < NLABEL; ++ll) {
    const float v = outp[ll * NSTATE + s] * LOG2E;
    const float lm = wave_max64(v);
    const float lsum = wave_sum64(EXP2(v - lm));
    const float y = v - lm - LOG2(lsum) + f;
    const float m = wave_max64(y);
    const float ssum = wave_sum64(EXP2(y - m));
    if (s == 0)
      score[b * NLABEL + ll] = (float)((MUt + (double)m + (double)LOG2(ssum)) * LN2_D);
  }
}

extern "C" void kernel_launch(void* const* d_in, const int* in_sizes, int n_in,
                              void* d_out, int out_size, void* d_ws, size_t ws_size,
                              hipStream_t stream) {
  const int* sents = (const int*)d_in[0];
  const int* length = (const int*)d_in[1];
  const float* emb = (const float*)d_in[2];
  const float* trans = (const float*)d_in[3];
  const float* outp = (const float*)d_in[4];
  float* score = (float*)d_out;

  // ws layout
  const size_t emb2_off = 0;
  const size_t emb2_sz = (size_t)VOCAB * NSTATE * sizeof(float);            // 8,192,000
  const size_t W_off = emb2_off + emb2_sz;
  const size_t W_sz = NSTATE * NSTATE * sizeof(float);                      // 16,384
  const size_t out2_off = W_off + W_sz;
  const size_t out2_sz = NLABEL * NSTATE * sizeof(float);                   // 4,096
  const size_t Mexp_off = out2_off + out2_sz;
  const size_t Mexp_sz = (size_t)BATCH * NC * sizeof(int);                  // 16,384
  const size_t Mout_off = Mexp_off + Mexp_sz;
  const size_t Mout_sz = (size_t)BATCH * NC * 4096 * sizeof(unsigned short);// 33,554,432
  const size_t need = Mout_off + Mout_sz;                                   // ~41.8 MB

  if (ws_size >= need) {
    float* emb2 = (float*)((char*)d_ws + emb2_off);
    float* W = (float*)((char*)d_ws + W_off);
    float* out2 = (float*)((char*)d_ws + out2_off);
    int* Mexp = (int*)((char*)d_ws + Mexp_off);
    unsigned short* Mout = (unsigned short*)((char*)d_ws + Mout_off);

    prep_emb_k<<<VOCAB / 4, 256, 0, stream>>>(emb, emb2);
    prep_mats_k<<<NSTATE + NLABEL, 64, 0, stream>>>(trans, outp, W, out2);
    phaseA_k<<<BATCH * NC / 4, 256, 0, stream>>>(sents, length, emb2, W, Mout, Mexp);
    phaseB_k<<<BATCH, 64, 0, stream>>>(sents, length, emb2, out2, Mout, Mexp, score);
  } else {
    iohmm_fwd_fb<<<BATCH, 64, 0, stream>>>(sents, length, emb, trans, outp, score);
  }
}